// Round 6
// baseline (212.440 us; speedup 1.0000x reference)
//
#include <hip/hip_runtime.h>
#include <hip/hip_bf16.h>

// MultiHeadAttention: B=2, S=2048, D=1024, H=16, key=head=64
// transpose_w (W->W^T bf16, Wq pre-scaled 0.125*log2e)
// proj_gemm  (fp32 X staged via global_load_lds, cvt at frag read; z==2 writes
//             V^T directly in attn frag layout, kappa-permuted + mask-zeroed)
// mask_prep  (kappa-ordered bf16 mask vector)
// attn_fwd   (S^T register-P flash, key-split=2)  ->  combine

#define SEQ 2048
#define DIM 1024
#define NPROJ 1024

typedef __bf16 bf16x8 __attribute__((ext_vector_type(8)));
typedef float floatx4 __attribute__((ext_vector_type(4)));
typedef float floatx16 __attribute__((ext_vector_type(16)));
typedef unsigned uintx4 __attribute__((ext_vector_type(4)));

__device__ inline unsigned short f2bf_bits(float x) {
  __hip_bfloat16 h = __float2bfloat16(x);
  return __builtin_bit_cast(unsigned short, h);
}

__device__ __forceinline__ void gload_lds16(const void* g, void* l) {
  __builtin_amdgcn_global_load_lds((const __attribute__((address_space(1))) void*)g,
                                   (__attribute__((address_space(3))) void*)l, 16, 0, 0);
}
__device__ __forceinline__ void gload_lds4(const void* g, void* l) {
  __builtin_amdgcn_global_load_lds((const __attribute__((address_space(1))) void*)g,
                                   (__attribute__((address_space(3))) void*)l, 4, 0, 0);
}

// ---------------------------------------------------------------------------
// Kernel 1: W [1024x1024] fp32 -> W^T bf16; Wq scaled by 0.125*log2e
// ---------------------------------------------------------------------------
__global__ __launch_bounds__(256) void transpose_w(
    const float* __restrict__ Wq, const float* __restrict__ Wk, const float* __restrict__ Wv,
    unsigned short* __restrict__ WqT, unsigned short* __restrict__ WkT, unsigned short* __restrict__ WvT)
{
  const float* W = blockIdx.z == 0 ? Wq : (blockIdx.z == 1 ? Wk : Wv);
  unsigned short* WT = blockIdx.z == 0 ? WqT : (blockIdx.z == 1 ? WkT : WvT);
  const float sc = (blockIdx.z == 0) ? 0.1803368801f : 1.0f;
  __shared__ float tile[64][65];
  const int k0 = blockIdx.x * 64;
  const int n0 = blockIdx.y * 64;
  const int t = threadIdx.x;
  #pragma unroll
  for (int it = 0; it < 4; ++it) {
    int idx = t + (it << 8);
    int r = idx >> 4, c4 = (idx & 15) << 2;
    float4 v = *reinterpret_cast<const float4*>(&W[(k0 + r) * DIM + n0 + c4]);
    tile[r][c4 + 0] = v.x; tile[r][c4 + 1] = v.y;
    tile[r][c4 + 2] = v.z; tile[r][c4 + 3] = v.w;
  }
  __syncthreads();
  #pragma unroll
  for (int it = 0; it < 4; ++it) {
    int idx = t + (it << 8);
    int r = idx >> 4, c4 = (idx & 15) << 2;
    ushort4 o;
    o.x = f2bf_bits(tile[c4 + 0][r] * sc);
    o.y = f2bf_bits(tile[c4 + 1][r] * sc);
    o.z = f2bf_bits(tile[c4 + 2][r] * sc);
    o.w = f2bf_bits(tile[c4 + 3][r] * sc);
    *reinterpret_cast<ushort4*>(&WT[(n0 + r) * DIM + k0 + c4]) = o;
  }
}

// ---------------------------------------------------------------------------
// Kernel 2: Y = bf16( X @ W ), X fp32 [4096x1024] staged via global_load_lds,
// cvt->bf16 at frag read. B = W^T bf16. 128x128 tile, BK=32, dbuf, 48 KB LDS.
// z==0 -> qw rows, z==1 -> kw rows, z==2 -> vT (attn frag layout, kappa keys,
// mask-zeroed) via epilogue LDS re-tile. XCD grid: x = m-tile.
// ---------------------------------------------------------------------------
__global__ __launch_bounds__(256, 3) void proj_gemm(
    const float* __restrict__ qi, const float* __restrict__ ki, const float* __restrict__ vi,
    const unsigned short* __restrict__ WqT, const unsigned short* __restrict__ WkT,
    const unsigned short* __restrict__ WvT, const int* __restrict__ vmask,
    unsigned short* __restrict__ qw, unsigned short* __restrict__ kw,
    unsigned short* __restrict__ vT)
{
  const int z = blockIdx.z;
  const float* X = z == 0 ? qi : (z == 1 ? ki : vi);
  const unsigned short* WT = z == 0 ? WqT : (z == 1 ? WkT : WvT);

  __shared__ float Al[2][128 * 32];            // fp32 A, 128B rows, swizzled chunks (32 KB)
  __shared__ unsigned short Bl[2][128 * 32];   // bf16 B, 64B rows, swizzled (16 KB)

  const int m0 = blockIdx.x * 128, n0 = blockIdx.y * 128;
  const int t = threadIdx.x;
  const int lane = t & 63;
  const int wid = t >> 6;
  const int wm = (wid >> 1) << 6, wn = (wid & 1) << 6;
  const int qd = lane >> 4, ln = lane & 15;

  auto stage = [&](int ks, int bi) {
    #pragma unroll
    for (int i = 0; i < 4; ++i) {              // A: 128 rows x 128B (fp32)
      int p = t + (i << 8);
      int r = p >> 3, c = p & 7;
      gload_lds16((const char*)X + (size_t)(m0 + r) * 4096 + ks * 128 + ((c ^ (r & 7)) << 4),
                  (char*)&Al[bi][0] + p * 16);
    }
    #pragma unroll
    for (int i = 0; i < 2; ++i) {              // B: 128 rows x 64B (bf16)
      int p = t + (i << 8);
      int r = p >> 2, c = p & 3;
      int f = (r + (r >> 2)) & 3;
      gload_lds16((const char*)WT + (size_t)(n0 + r) * 2048 + ks * 64 + ((c ^ f) << 4),
                  (char*)&Bl[bi][0] + p * 16);
    }
  };

  floatx4 acc[4][4] = {};
  stage(0, 0);

  for (int ks = 0; ks < 32; ++ks) {
    __syncthreads();
    if (ks + 1 < 32) stage(ks + 1, (ks + 1) & 1);
    const int bi = ks & 1;
    bf16x8 af[4], bfr[4];
    #pragma unroll
    for (int mb = 0; mb < 4; ++mb) {
      int m = wm + mb * 16 + ln;
      int g0 = (qd * 2) ^ (m & 7);
      int g1 = (qd * 2 + 1) ^ (m & 7);
      float4 fa = *reinterpret_cast<const float4*>(&Al[bi][m * 32 + g0 * 4]);
      float4 fb = *reinterpret_cast<const float4*>(&Al[bi][m * 32 + g1 * 4]);
      af[mb][0] = (__bf16)fa.x; af[mb][1] = (__bf16)fa.y;
      af[mb][2] = (__bf16)fa.z; af[mb][3] = (__bf16)fa.w;
      af[mb][4] = (__bf16)fb.x; af[mb][5] = (__bf16)fb.y;
      af[mb][6] = (__bf16)fb.z; af[mb][7] = (__bf16)fb.w;
    }
    #pragma unroll
    for (int nb = 0; nb < 4; ++nb) {
      int n = wn + nb * 16 + ln;
      int fn = (n + (n >> 2)) & 3;
      bfr[nb] = *reinterpret_cast<const bf16x8*>(&Bl[bi][n * 32 + ((qd ^ fn) << 3)]);
    }
    #pragma unroll
    for (int mb = 0; mb < 4; ++mb)
      #pragma unroll
      for (int nb = 0; nb < 4; ++nb)
        acc[mb][nb] = __builtin_amdgcn_mfma_f32_16x16x32_bf16(af[mb], bfr[nb], acc[mb][nb], 0, 0, 0);
  }

  if (z < 2) {
    unsigned short* Y = z == 0 ? qw : kw;
    #pragma unroll
    for (int mb = 0; mb < 4; ++mb)
      #pragma unroll
      for (int nb = 0; nb < 4; ++nb)
        #pragma unroll
        for (int i = 0; i < 4; ++i) {
          int m = m0 + wm + mb * 16 + qd * 4 + i;
          int n = n0 + wn + nb * 16 + ln;
          Y[(size_t)m * NPROJ + n] = f2bf_bits(acc[mb][nb][i]);
        }
  } else {
    // V^T epilogue: re-tile acc into attn frag layout via LDS, mask-zeroed.
    __syncthreads();                            // k-loop LDS reads complete
    unsigned short* T = (unsigned short*)&Al[0][0];   // 16384 ushorts = 32 KB
    unsigned short* M = &Bl[0][0];                    // 128 mask words
    if (t < 128) M[t] = vmask[m0 + t] ? 0xFFFFu : 0u;
    __syncthreads();
    #pragma unroll
    for (int mb = 0; mb < 4; ++mb)
      #pragma unroll
      for (int nb = 0; nb < 4; ++nb)
        #pragma unroll
        for (int i = 0; i < 4; ++i) {
          int mloc = wm + mb * 16 + qd * 4 + i;     // key row in tile (0..127)
          int n = wn + nb * 16 + ln;                // 0..127: h_loc*64 + d
          int kt_loc = mloc >> 6, s6 = mloc & 63;
          int kstep = s6 >> 4, k16 = s6 & 15;
          int hi = (k16 >> 2) & 1;
          int j = (k16 & 3) | (((k16 >> 3) & 1) << 2);
          int page = kt_loc * 2 + (n >> 6);
          int sg = kstep * 2 + hi;
          int off = ((page * 8 + sg) * 64 + (n & 63)) * 8 + j;
          T[off] = f2bf_bits(acc[mb][nb][i]) & M[mloc];
        }
    __syncthreads();
    const int b = m0 >> 11;
    #pragma unroll
    for (int it = 0; it < 8; ++it) {
      int s = t + (it << 8);                      // 2048 slots of 16B
      int page = s >> 9, insl = s & 511;
      int kt_g = ((blockIdx.x & 15) << 1) + (page >> 1);
      int bh = b * 16 + blockIdx.y * 2 + (page & 1);
      *reinterpret_cast<int4*>(&vT[(size_t)(bh * 32 + kt_g) * 4096 + insl * 8]) =
          *reinterpret_cast<const int4*>(&T[s * 8]);
    }
  }
}

// ---------------------------------------------------------------------------
// Kernel 3: kappa-ordered bf16 mask vector mkT[b][kt*64 + slot]
// ---------------------------------------------------------------------------
__global__ __launch_bounds__(256) void mask_prep(
    const int* __restrict__ vmask, unsigned short* __restrict__ mkT)
{
  int idx = blockIdx.x * 256 + threadIdx.x;     // 4096 entries
  int b = idx >> 11, pos = idx & 2047;
  int kt = pos >> 6, t64 = pos & 63;
  int kstep = t64 >> 4, s16 = t64 & 15, hi = s16 >> 3, j = s16 & 7;
  int key16 = (j & 3) + 8 * (j >> 2) + 4 * hi;
  mkT[idx] = vmask[b * SEQ + kt * 64 + kstep * 16 + key16] ? 0x3F80u : 0u;
}

// ---------------------------------------------------------------------------
// Kernel 4: flash attention, S^T register-P. grid (bh=32, qt=16, split=2),
// 256 thr = 4 waves x 32 queries. MFMA 32x32x16.
// ---------------------------------------------------------------------------
__global__ __launch_bounds__(256, 4) void attn_fwd(
    const unsigned short* __restrict__ qw, const unsigned short* __restrict__ kw,
    const unsigned short* __restrict__ vT, const unsigned short* __restrict__ mkT,
    float* __restrict__ out, float* __restrict__ Opart1, float* __restrict__ lpart)
{
  __shared__ unsigned short Kl[2][4096];   // [sg=dgroup*2+dhi][key64][8]
  __shared__ unsigned short Vl[2][4096];   // [sg=kstep*2+dhi][d64][8]
  __shared__ unsigned short mkl[2][64];

  const int t = threadIdx.x, lane = t & 63, wid = t >> 6;
  const int l31 = lane & 31, hi = lane >> 5;
  const int bh = blockIdx.x, qt = blockIdx.y, sp = blockIdx.z;
  const int b = bh >> 4, h = bh & 15;
  const int base = b * SEQ;
  const int qblk = qt * 4 + wid;
  const int kt0 = sp * 16;

  bf16x8 qf[4];
  #pragma unroll
  for (int ks = 0; ks < 4; ++ks)
    qf[ks] = *reinterpret_cast<const bf16x8*>(
        &qw[(size_t)(base + qblk * 32 + l31) * NPROJ + h * 64 + ks * 16 + hi * 8]);

  auto stage = [&](int kt, int bi) {
    #pragma unroll
    for (int i = 0; i < 2; ++i) {
      int p = t + (i << 8);
      int key = p & 63, og = p >> 6;
      gload_lds16((const char*)&kw[(size_t)(base + kt * 64 + key) * NPROJ + h * 64 + og * 8],
                  (char*)&Kl[bi][0] + p * 16);
      gload_lds16((const char*)&vT[(size_t)(bh * 32 + kt) * 4096 + p * 8],
                  (char*)&Vl[bi][0] + p * 16);
    }
    if (t < 32)
      gload_lds4((const char*)(mkT + (size_t)b * SEQ + kt * 64) + t * 4,
                 (char*)&mkl[bi][0] + t * 4);
  };

  floatx16 oa[2] = {};
  floatx16 la = {};
  stage(kt0, 0);

  for (int it = 0; it < 16; ++it) {
    __syncthreads();
    if (it + 1 < 16) stage(kt0 + it + 1, (it + 1) & 1);
    const int bi = it & 1;

    floatx16 s[2] = {};
    #pragma unroll
    for (int ks = 0; ks < 4; ++ks) {
      const unsigned short* kb = &Kl[bi][(ks * 2 + hi) * 512];
      bf16x8 k0 = *reinterpret_cast<const bf16x8*>(&kb[l31 * 8]);
      bf16x8 k1 = *reinterpret_cast<const bf16x8*>(&kb[(32 + l31) * 8]);
      s[0] = __builtin_amdgcn_mfma_f32_32x32x16_bf16(k0, qf[ks], s[0], 0, 0, 0);
      s[1] = __builtin_amdgcn_mfma_f32_32x32x16_bf16(k1, qf[ks], s[1], 0, 0, 0);
    }

    unsigned pk[16];
    #pragma unroll
    for (int mb = 0; mb < 2; ++mb)
      #pragma unroll
      for (int r8 = 0; r8 < 2; ++r8)
        #pragma unroll
        for (int i = 0; i < 4; ++i) {
          float a = __builtin_amdgcn_exp2f(s[mb][r8 * 8 + i * 2]);
          float c = __builtin_amdgcn_exp2f(s[mb][r8 * 8 + i * 2 + 1]);
          unsigned ua = __builtin_bit_cast(unsigned, a) + 0x8000u;
          unsigned uc = __builtin_bit_cast(unsigned, c) + 0x8000u;
          pk[mb * 8 + r8 * 4 + i] = __builtin_amdgcn_perm(uc, ua, 0x07060302u);
        }

    #pragma unroll
    for (int kk = 0; kk < 4; ++kk) {
      uintx4 pv = {pk[kk * 4], pk[kk * 4 + 1], pk[kk * 4 + 2], pk[kk * 4 + 3]};
      bf16x8 pb = __builtin_bit_cast(bf16x8, pv);
      const unsigned short* vb = &Vl[bi][(kk * 2 + hi) * 512];
      bf16x8 v0 = *reinterpret_cast<const bf16x8*>(&vb[l31 * 8]);
      bf16x8 v1 = *reinterpret_cast<const bf16x8*>(&vb[(32 + l31) * 8]);
      bf16x8 mf = *reinterpret_cast<const bf16x8*>(&mkl[bi][kk * 16 + hi * 8]);
      oa[0] = __builtin_amdgcn_mfma_f32_32x32x16_bf16(v0, pb, oa[0], 0, 0, 0);
      oa[1] = __builtin_amdgcn_mfma_f32_32x32x16_bf16(v1, pb, oa[1], 0, 0, 0);
      la    = __builtin_amdgcn_mfma_f32_32x32x16_bf16(mf, pb, la, 0, 0, 0);
    }
  }

  if (sp == 0) {
    size_t tb = (size_t)(base + qblk * 32) * NPROJ + h * 64;
    #pragma unroll
    for (int mb = 0; mb < 2; ++mb)
      #pragma unroll
      for (int r = 0; r < 16; ++r)
        out[tb + (size_t)(mb * 16 + r) * NPROJ + lane] = oa[mb][r];
    if (lane < 32)
      lpart[((size_t)bh * 64 + qblk) * 32 + l31] = la[0];
  } else {
    float* dst = Opart1 + ((size_t)bh * 64 + qblk) * 2048;
    #pragma unroll
    for (int mb = 0; mb < 2; ++mb)
      #pragma unroll
      for (int r = 0; r < 16; ++r)
        dst[(mb * 16 + r) * 64 + lane] = oa[mb][r];
    if (lane < 32)
      lpart[((size_t)(32 + bh) * 64 + qblk) * 32 + l31] = la[0];
  }
}

// ---------------------------------------------------------------------------
// Kernel 5: combine split partials, normalize, unscramble. grid (qblk64, bh32).
// ---------------------------------------------------------------------------
__global__ __launch_bounds__(256) void combine(
    const float* __restrict__ Opart1, const float* __restrict__ lpart,
    float* __restrict__ out)
{
  __shared__ float Os[32][68];
  __shared__ float ls[32];
  const int qblk = blockIdx.x, bh = blockIdx.y;
  const int b = bh >> 4, h = bh & 15, t = threadIdx.x;
  size_t tb = (size_t)(b * SEQ + qblk * 32) * NPROJ + h * 64;
  const float* o1 = Opart1 + ((size_t)bh * 64 + qblk) * 2048;
  if (t < 32)
    ls[t] = lpart[((size_t)bh * 64 + qblk) * 32 + t] +
            lpart[((size_t)(32 + bh) * 64 + qblk) * 32 + t];
  float v[8];
  int dd[8], qq[8];
  #pragma unroll
  for (int i = 0; i < 8; ++i) {
    int f = t + (i << 8);
    int ln = f & 63, mr = f >> 6;
    int mb = mr >> 4, reg = mr & 15;
    v[i] = out[tb + (size_t)mr * NPROJ + ln] + o1[f];
    dd[i] = (reg & 3) + ((reg >> 2) & 3) * 8 + (ln >> 5) * 4 + mb * 32;
    qq[i] = ln & 31;
  }
  __syncthreads();
  #pragma unroll
  for (int i = 0; i < 8; ++i) Os[qq[i]][dd[i]] = v[i];
  __syncthreads();
  #pragma unroll
  for (int i = 0; i < 2; ++i) {
    int p = t + (i << 8);
    int q = p >> 4, c = p & 15;
    float inv = 1.0f / ls[q];
    float4 o = *reinterpret_cast<const float4*>(&Os[q][c * 4]);
    o.x *= inv; o.y *= inv; o.z *= inv; o.w *= inv;
    *reinterpret_cast<float4*>(&out[tb + (size_t)q * NPROJ + c * 4]) = o;
  }
}

// ---------------------------------------------------------------------------
extern "C" void kernel_launch(void* const* d_in, const int* in_sizes, int n_in,
                              void* d_out, int out_size, void* d_ws, size_t ws_size,
                              hipStream_t stream) {
  const float* q  = (const float*)d_in[0];
  const float* k  = (const float*)d_in[1];
  const float* v  = (const float*)d_in[2];
  const int* vm   = (const int*)d_in[3];
  const float* Wq = (const float*)d_in[4];
  const float* Wk = (const float*)d_in[5];
  const float* Wv = (const float*)d_in[6];
  float* out = (float*)d_out;

  unsigned short* ws = (unsigned short*)d_ws;
  unsigned short* WqT = ws;                        // 2 MB each
  unsigned short* WkT = ws + ((size_t)1 << 20);
  unsigned short* WvT = ws + ((size_t)2 << 20);
  unsigned short* qw  = ws + ((size_t)3 << 20);    // 8 MB
  unsigned short* kw  = ws + ((size_t)7 << 20);    // 8 MB
  unsigned short* vT  = ws + ((size_t)11 << 20);   // 8 MB (exactly 4M ushorts)
  unsigned short* mkT = ws + ((size_t)15 << 20);   // 8 KB
  float* lpart  = (float*)(ws + ((size_t)15 << 20) + 65536);   // 512 KB
  float* Opart1 = (float*)(ws + ((size_t)16 << 20));           // 16.78 MB

  transpose_w<<<dim3(16, 16, 3), 256, 0, stream>>>(Wq, Wk, Wv, WqT, WkT, WvT);
  proj_gemm<<<dim3(32, 8, 3), 256, 0, stream>>>(q, k, v, WqT, WkT, WvT, vm, qw, kw, vT);
  mask_prep<<<16, 256, 0, stream>>>(vm, mkT);
  attn_fwd<<<dim3(32, 16, 2), 256, 0, stream>>>(qw, kw, vT, mkT, out, Opart1, lpart);
  combine<<<dim3(64, 32), 256, 0, stream>>>(Opart1, lpart, out);
}

// Round 7
// 208.890 us; speedup vs baseline: 1.0170x; 1.0170x over previous
//
#include <hip/hip_runtime.h>
#include <hip/hip_bf16.h>

// MultiHeadAttention: B=2, S=2048, D=1024, H=16, key=head=64
// transpose_w (W->W^T bf16, Wq pre-scaled 0.125*log2e; fused kappa mask prep)
// proj_gemm  (A: fp32 global->VGPR->cvt->bf16 LDS, dbuf; B: async global_load_lds;
//             z==2 writes V^T directly in attn frag layout, mask-zeroed)
// attn_fwd   (S^T register-P flash, key-split=2)  ->  combine

#define SEQ 2048
#define DIM 1024
#define NPROJ 1024

typedef __bf16 bf16x8 __attribute__((ext_vector_type(8)));
typedef float floatx4 __attribute__((ext_vector_type(4)));
typedef float floatx16 __attribute__((ext_vector_type(16)));
typedef unsigned uintx4 __attribute__((ext_vector_type(4)));

__device__ inline unsigned short f2bf_bits(float x) {
  __hip_bfloat16 h = __float2bfloat16(x);
  return __builtin_bit_cast(unsigned short, h);
}

__device__ __forceinline__ void gload_lds16(const void* g, void* l) {
  __builtin_amdgcn_global_load_lds((const __attribute__((address_space(1))) void*)g,
                                   (__attribute__((address_space(3))) void*)l, 16, 0, 0);
}
__device__ __forceinline__ void gload_lds4(const void* g, void* l) {
  __builtin_amdgcn_global_load_lds((const __attribute__((address_space(1))) void*)g,
                                   (__attribute__((address_space(3))) void*)l, 4, 0, 0);
}

// ---------------------------------------------------------------------------
// Kernel 1: W [1024x1024] fp32 -> W^T bf16; Wq scaled by 0.125*log2e.
// Fused: kappa-ordered bf16 mask vector mkT (on z==2, y==0, x<16 blocks).
// ---------------------------------------------------------------------------
__global__ __launch_bounds__(256) void transpose_w(
    const float* __restrict__ Wq, const float* __restrict__ Wk, const float* __restrict__ Wv,
    unsigned short* __restrict__ WqT, unsigned short* __restrict__ WkT,
    unsigned short* __restrict__ WvT,
    const int* __restrict__ vmask, unsigned short* __restrict__ mkT)
{
  const float* W = blockIdx.z == 0 ? Wq : (blockIdx.z == 1 ? Wk : Wv);
  unsigned short* WT = blockIdx.z == 0 ? WqT : (blockIdx.z == 1 ? WkT : WvT);
  const float sc = (blockIdx.z == 0) ? 0.1803368801f : 1.0f;
  __shared__ float tile[64][65];
  const int k0 = blockIdx.x * 64;
  const int n0 = blockIdx.y * 64;
  const int t = threadIdx.x;
  if (blockIdx.z == 2 && blockIdx.y == 0 && blockIdx.x < 16) {
    int idx = blockIdx.x * 256 + t;             // 4096 entries
    int b = idx >> 11, pos = idx & 2047;
    int kt = pos >> 6, t64 = pos & 63;
    int kstep = t64 >> 4, s16 = t64 & 15, hi = s16 >> 3, j = s16 & 7;
    int key16 = (j & 3) + 8 * (j >> 2) + 4 * hi;
    mkT[idx] = vmask[b * SEQ + kt * 64 + kstep * 16 + key16] ? 0x3F80u : 0u;
  }
  #pragma unroll
  for (int it = 0; it < 4; ++it) {
    int idx = t + (it << 8);
    int r = idx >> 4, c4 = (idx & 15) << 2;
    float4 v = *reinterpret_cast<const float4*>(&W[(k0 + r) * DIM + n0 + c4]);
    tile[r][c4 + 0] = v.x; tile[r][c4 + 1] = v.y;
    tile[r][c4 + 2] = v.z; tile[r][c4 + 3] = v.w;
  }
  __syncthreads();
  #pragma unroll
  for (int it = 0; it < 4; ++it) {
    int idx = t + (it << 8);
    int r = idx >> 4, c4 = (idx & 15) << 2;
    ushort4 o;
    o.x = f2bf_bits(tile[c4 + 0][r] * sc);
    o.y = f2bf_bits(tile[c4 + 1][r] * sc);
    o.z = f2bf_bits(tile[c4 + 2][r] * sc);
    o.w = f2bf_bits(tile[c4 + 3][r] * sc);
    *reinterpret_cast<ushort4*>(&WT[(n0 + r) * DIM + k0 + c4]) = o;
  }
}

// ---------------------------------------------------------------------------
// Kernel 2: Y = bf16( X @ W ), X fp32. A: global->VGPR->bf16->ds_write (dbuf);
// B: W^T bf16 via async global_load_lds. 128x128 tile, BK=32, 32 KB LDS.
// z==0 -> qw, z==1 -> kw, z==2 -> vT (attn frag layout, kappa keys, mask-zeroed).
// ---------------------------------------------------------------------------
__global__ __launch_bounds__(256, 4) void proj_gemm(
    const float* __restrict__ qi, const float* __restrict__ ki, const float* __restrict__ vi,
    const unsigned short* __restrict__ WqT, const unsigned short* __restrict__ WkT,
    const unsigned short* __restrict__ WvT, const int* __restrict__ vmask,
    unsigned short* __restrict__ qw, unsigned short* __restrict__ kw,
    unsigned short* __restrict__ vT)
{
  const int z = blockIdx.z;
  const float* X = z == 0 ? qi : (z == 1 ? ki : vi);
  const unsigned short* WT = z == 0 ? WqT : (z == 1 ? WkT : WvT);

  __shared__ unsigned short S[4][4096];   // A: S[0],S[1]; B: S[2],S[3]  (32 KB)
  __shared__ unsigned short Msk[128];

  const int m0 = blockIdx.x * 128, n0 = blockIdx.y * 128;
  const int t = threadIdx.x;
  const int lane = t & 63;
  const int wid = t >> 6;
  const int wm = (wid >> 1) << 6, wn = (wid & 1) << 6;
  const int qd = lane >> 4, ln = lane & 15;

  // A register staging: thread t owns row ar = t>>1, 16-float half ah = t&1
  const int ar = t >> 1, ah = t & 1;
  const float* Arow = X + (size_t)(m0 + ar) * DIM + ah * 16;
  const int fr = (ar + (ar >> 2)) & 3;
  const int wof0 = ar * 32 + (((2 * ah + 0) ^ fr) << 3);
  const int wof1 = ar * 32 + (((2 * ah + 1) ^ fr) << 3);

  auto stageB = [&](int ks, int bi) {
    #pragma unroll
    for (int i = 0; i < 2; ++i) {
      int p = t + (i << 8);
      int r = p >> 2, c = p & 3;
      int f = (r + (r >> 2)) & 3;
      gload_lds16((const char*)WT + (size_t)(n0 + r) * 2048 + ks * 64 + ((c ^ f) << 4),
                  (char*)&S[2 + bi][0] + p * 16);
    }
  };

  float4 a0, a1, a2, a3;
  auto loadA = [&](int ks) {
    const float* p = Arow + ks * 32;
    a0 = *reinterpret_cast<const float4*>(p + 0);
    a1 = *reinterpret_cast<const float4*>(p + 4);
    a2 = *reinterpret_cast<const float4*>(p + 8);
    a3 = *reinterpret_cast<const float4*>(p + 12);
  };
  auto writeA = [&](int bi) {
    bf16x8 v0, v1;
    v0[0] = (__bf16)a0.x; v0[1] = (__bf16)a0.y; v0[2] = (__bf16)a0.z; v0[3] = (__bf16)a0.w;
    v0[4] = (__bf16)a1.x; v0[5] = (__bf16)a1.y; v0[6] = (__bf16)a1.z; v0[7] = (__bf16)a1.w;
    v1[0] = (__bf16)a2.x; v1[1] = (__bf16)a2.y; v1[2] = (__bf16)a2.z; v1[3] = (__bf16)a2.w;
    v1[4] = (__bf16)a3.x; v1[5] = (__bf16)a3.y; v1[6] = (__bf16)a3.z; v1[7] = (__bf16)a3.w;
    *reinterpret_cast<bf16x8*>(&S[bi][wof0]) = v0;
    *reinterpret_cast<bf16x8*>(&S[bi][wof1]) = v1;
  };

  floatx4 acc[4][4] = {};
  stageB(0, 0);
  loadA(0);
  writeA(0);
  __syncthreads();

  for (int ks = 0; ks < 32; ++ks) {
    const int bi = ks & 1;
    if (ks + 1 < 32) { stageB(ks + 1, bi ^ 1); loadA(ks + 1); }
    bf16x8 af[4], bfr[4];
    #pragma unroll
    for (int mb = 0; mb < 4; ++mb) {
      int m = wm + mb * 16 + ln;
      int fm = (m + (m >> 2)) & 3;
      af[mb] = *reinterpret_cast<const bf16x8*>(&S[bi][m * 32 + ((qd ^ fm) << 3)]);
    }
    #pragma unroll
    for (int nb = 0; nb < 4; ++nb) {
      int n = wn + nb * 16 + ln;
      int fn = (n + (n >> 2)) & 3;
      bfr[nb] = *reinterpret_cast<const bf16x8*>(&S[2 + bi][n * 32 + ((qd ^ fn) << 3)]);
    }
    #pragma unroll
    for (int mb = 0; mb < 4; ++mb)
      #pragma unroll
      for (int nb = 0; nb < 4; ++nb)
        acc[mb][nb] = __builtin_amdgcn_mfma_f32_16x16x32_bf16(af[mb], bfr[nb], acc[mb][nb], 0, 0, 0);
    if (ks + 1 < 32) writeA(bi ^ 1);
    __syncthreads();
  }

  if (z < 2) {
    unsigned short* Y = z == 0 ? qw : kw;
    #pragma unroll
    for (int mb = 0; mb < 4; ++mb)
      #pragma unroll
      for (int nb = 0; nb < 4; ++nb)
        #pragma unroll
        for (int i = 0; i < 4; ++i) {
          int m = m0 + wm + mb * 16 + qd * 4 + i;
          int n = n0 + wn + nb * 16 + ln;
          Y[(size_t)m * NPROJ + n] = f2bf_bits(acc[mb][nb][i]);
        }
  } else {
    // V^T epilogue: re-tile acc into attn frag layout via LDS, mask-zeroed.
    unsigned short* T = &S[0][0];                 // 16384 ushorts = 32 KB
    if (t < 128) Msk[t] = vmask[m0 + t] ? 0xFFFFu : 0u;
    __syncthreads();
    #pragma unroll
    for (int mb = 0; mb < 4; ++mb)
      #pragma unroll
      for (int nb = 0; nb < 4; ++nb)
        #pragma unroll
        for (int i = 0; i < 4; ++i) {
          int mloc = wm + mb * 16 + qd * 4 + i;   // key row in tile (0..127)
          int n = wn + nb * 16 + ln;              // h_loc*64 + d
          int kt_loc = mloc >> 6, s6 = mloc & 63;
          int kstep = s6 >> 4, k16 = s6 & 15;
          int hi = (k16 >> 2) & 1;
          int j = (k16 & 3) | (((k16 >> 3) & 1) << 2);
          int page = kt_loc * 2 + (n >> 6);
          int sg = kstep * 2 + hi;
          int off = ((page * 8 + sg) * 64 + (n & 63)) * 8 + j;
          T[off] = f2bf_bits(acc[mb][nb][i]) & Msk[mloc];
        }
    __syncthreads();
    const int b = m0 >> 11;
    #pragma unroll
    for (int it = 0; it < 8; ++it) {
      int s = t + (it << 8);                      // 2048 slots of 16B
      int page = s >> 9, insl = s & 511;
      int kt_g = ((blockIdx.x & 15) << 1) + (page >> 1);
      int bh = b * 16 + blockIdx.y * 2 + (page & 1);
      *reinterpret_cast<int4*>(&vT[(size_t)(bh * 32 + kt_g) * 4096 + insl * 8]) =
          *reinterpret_cast<const int4*>(&T[s * 8]);
    }
  }
}

// ---------------------------------------------------------------------------
// Kernel 4: flash attention, S^T register-P. grid (bh=32, qt=16, split=2),
// 256 thr = 4 waves x 32 queries. MFMA 32x32x16.
// ---------------------------------------------------------------------------
__global__ __launch_bounds__(256, 4) void attn_fwd(
    const unsigned short* __restrict__ qw, const unsigned short* __restrict__ kw,
    const unsigned short* __restrict__ vT, const unsigned short* __restrict__ mkT,
    float* __restrict__ out, float* __restrict__ Opart1, float* __restrict__ lpart)
{
  __shared__ unsigned short Kl[2][4096];   // [sg=dgroup*2+dhi][key64][8]
  __shared__ unsigned short Vl[2][4096];   // [sg=kstep*2+dhi][d64][8]
  __shared__ unsigned short mkl[2][64];

  const int t = threadIdx.x, lane = t & 63, wid = t >> 6;
  const int l31 = lane & 31, hi = lane >> 5;
  const int bh = blockIdx.x, qt = blockIdx.y, sp = blockIdx.z;
  const int b = bh >> 4, h = bh & 15;
  const int base = b * SEQ;
  const int qblk = qt * 4 + wid;
  const int kt0 = sp * 16;

  bf16x8 qf[4];
  #pragma unroll
  for (int ks = 0; ks < 4; ++ks)
    qf[ks] = *reinterpret_cast<const bf16x8*>(
        &qw[(size_t)(base + qblk * 32 + l31) * NPROJ + h * 64 + ks * 16 + hi * 8]);

  auto stage = [&](int kt, int bi) {
    #pragma unroll
    for (int i = 0; i < 2; ++i) {
      int p = t + (i << 8);
      int key = p & 63, og = p >> 6;
      gload_lds16((const char*)&kw[(size_t)(base + kt * 64 + key) * NPROJ + h * 64 + og * 8],
                  (char*)&Kl[bi][0] + p * 16);
      gload_lds16((const char*)&vT[(size_t)(bh * 32 + kt) * 4096 + p * 8],
                  (char*)&Vl[bi][0] + p * 16);
    }
    if (t < 32)
      gload_lds4((const char*)(mkT + (size_t)b * SEQ + kt * 64) + t * 4,
                 (char*)&mkl[bi][0] + t * 4);
  };

  floatx16 oa[2] = {};
  floatx16 la = {};
  stage(kt0, 0);

  for (int it = 0; it < 16; ++it) {
    __syncthreads();
    if (it + 1 < 16) stage(kt0 + it + 1, (it + 1) & 1);
    const int bi = it & 1;

    floatx16 s[2] = {};
    #pragma unroll
    for (int ks = 0; ks < 4; ++ks) {
      const unsigned short* kb = &Kl[bi][(ks * 2 + hi) * 512];
      bf16x8 k0 = *reinterpret_cast<const bf16x8*>(&kb[l31 * 8]);
      bf16x8 k1 = *reinterpret_cast<const bf16x8*>(&kb[(32 + l31) * 8]);
      s[0] = __builtin_amdgcn_mfma_f32_32x32x16_bf16(k0, qf[ks], s[0], 0, 0, 0);
      s[1] = __builtin_amdgcn_mfma_f32_32x32x16_bf16(k1, qf[ks], s[1], 0, 0, 0);
    }

    unsigned pk[16];
    #pragma unroll
    for (int mb = 0; mb < 2; ++mb)
      #pragma unroll
      for (int r8 = 0; r8 < 2; ++r8)
        #pragma unroll
        for (int i = 0; i < 4; ++i) {
          float a = __builtin_amdgcn_exp2f(s[mb][r8 * 8 + i * 2]);
          float c = __builtin_amdgcn_exp2f(s[mb][r8 * 8 + i * 2 + 1]);
          unsigned ua = __builtin_bit_cast(unsigned, a) + 0x8000u;
          unsigned uc = __builtin_bit_cast(unsigned, c) + 0x8000u;
          pk[mb * 8 + r8 * 4 + i] = __builtin_amdgcn_perm(uc, ua, 0x07060302u);
        }

    #pragma unroll
    for (int kk = 0; kk < 4; ++kk) {
      uintx4 pv = {pk[kk * 4], pk[kk * 4 + 1], pk[kk * 4 + 2], pk[kk * 4 + 3]};
      bf16x8 pb = __builtin_bit_cast(bf16x8, pv);
      const unsigned short* vb = &Vl[bi][(kk * 2 + hi) * 512];
      bf16x8 v0 = *reinterpret_cast<const bf16x8*>(&vb[l31 * 8]);
      bf16x8 v1 = *reinterpret_cast<const bf16x8*>(&vb[(32 + l31) * 8]);
      bf16x8 mf = *reinterpret_cast<const bf16x8*>(&mkl[bi][kk * 16 + hi * 8]);
      oa[0] = __builtin_amdgcn_mfma_f32_32x32x16_bf16(v0, pb, oa[0], 0, 0, 0);
      oa[1] = __builtin_amdgcn_mfma_f32_32x32x16_bf16(v1, pb, oa[1], 0, 0, 0);
      la    = __builtin_amdgcn_mfma_f32_32x32x16_bf16(mf, pb, la, 0, 0, 0);
    }
  }

  if (sp == 0) {
    size_t tb = (size_t)(base + qblk * 32) * NPROJ + h * 64;
    #pragma unroll
    for (int mb = 0; mb < 2; ++mb)
      #pragma unroll
      for (int r = 0; r < 16; ++r)
        out[tb + (size_t)(mb * 16 + r) * NPROJ + lane] = oa[mb][r];
    if (lane < 32)
      lpart[((size_t)bh * 64 + qblk) * 32 + l31] = la[0];
  } else {
    float* dst = Opart1 + ((size_t)bh * 64 + qblk) * 2048;
    #pragma unroll
    for (int mb = 0; mb < 2; ++mb)
      #pragma unroll
      for (int r = 0; r < 16; ++r)
        dst[(mb * 16 + r) * 64 + lane] = oa[mb][r];
    if (lane < 32)
      lpart[((size_t)(32 + bh) * 64 + qblk) * 32 + l31] = la[0];
  }
}

// ---------------------------------------------------------------------------
// Kernel 5: combine split partials, normalize, unscramble. grid (qblk64, bh32).
// ---------------------------------------------------------------------------
__global__ __launch_bounds__(256) void combine(
    const float* __restrict__ Opart1, const float* __restrict__ lpart,
    float* __restrict__ out)
{
  __shared__ float Os[32][68];
  __shared__ float ls[32];
  const int qblk = blockIdx.x, bh = blockIdx.y;
  const int b = bh >> 4, h = bh & 15, t = threadIdx.x;
  size_t tb = (size_t)(b * SEQ + qblk * 32) * NPROJ + h * 64;
  const float* o1 = Opart1 + ((size_t)bh * 64 + qblk) * 2048;
  if (t < 32)
    ls[t] = lpart[((size_t)bh * 64 + qblk) * 32 + t] +
            lpart[((size_t)(32 + bh) * 64 + qblk) * 32 + t];
  float v[8];
  int dd[8], qq[8];
  #pragma unroll
  for (int i = 0; i < 8; ++i) {
    int f = t + (i << 8);
    int ln = f & 63, mr = f >> 6;
    int mb = mr >> 4, reg = mr & 15;
    v[i] = out[tb + (size_t)mr * NPROJ + ln] + o1[f];
    dd[i] = (reg & 3) + ((reg >> 2) & 3) * 8 + (ln >> 5) * 4 + mb * 32;
    qq[i] = ln & 31;
  }
  __syncthreads();
  #pragma unroll
  for (int i = 0; i < 8; ++i) Os[qq[i]][dd[i]] = v[i];
  __syncthreads();
  #pragma unroll
  for (int i = 0; i < 2; ++i) {
    int p = t + (i << 8);
    int q = p >> 4, c = p & 15;
    float inv = 1.0f / ls[q];
    float4 o = *reinterpret_cast<const float4*>(&Os[q][c * 4]);
    o.x *= inv; o.y *= inv; o.z *= inv; o.w *= inv;
    *reinterpret_cast<float4*>(&out[tb + (size_t)q * NPROJ + c * 4]) = o;
  }
}

// ---------------------------------------------------------------------------
extern "C" void kernel_launch(void* const* d_in, const int* in_sizes, int n_in,
                              void* d_out, int out_size, void* d_ws, size_t ws_size,
                              hipStream_t stream) {
  const float* q  = (const float*)d_in[0];
  const float* k  = (const float*)d_in[1];
  const float* v  = (const float*)d_in[2];
  const int* vm   = (const int*)d_in[3];
  const float* Wq = (const float*)d_in[4];
  const float* Wk = (const float*)d_in[5];
  const float* Wv = (const float*)d_in[6];
  float* out = (float*)d_out;

  unsigned short* ws = (unsigned short*)d_ws;
  unsigned short* WqT = ws;                        // 2 MB each
  unsigned short* WkT = ws + ((size_t)1 << 20);
  unsigned short* WvT = ws + ((size_t)2 << 20);
  unsigned short* qw  = ws + ((size_t)3 << 20);    // 8 MB
  unsigned short* kw  = ws + ((size_t)7 << 20);    // 8 MB
  unsigned short* vT  = ws + ((size_t)11 << 20);   // 8 MB
  unsigned short* mkT = ws + ((size_t)15 << 20);   // 8 KB
  float* lpart  = (float*)(ws + ((size_t)15 << 20) + 65536);   // 512 KB
  float* Opart1 = (float*)(ws + ((size_t)16 << 20));           // 16.78 MB

  transpose_w<<<dim3(16, 16, 3), 256, 0, stream>>>(Wq, Wk, Wv, WqT, WkT, WvT, vm, mkT);
  proj_gemm<<<dim3(32, 8, 3), 256, 0, stream>>>(q, k, v, WqT, WkT, WvT, vm, qw, kw, vT);
  attn_fwd<<<dim3(32, 16, 2), 256, 0, stream>>>(qw, kw, vT, mkT, out, Opart1, lpart);
  combine<<<dim3(64, 32), 256, 0, stream>>>(Opart1, lpart, out);
}